// Round 1
// baseline (40.480 us; speedup 1.0000x reference)
//
#include <hip/hip_runtime.h>
#include <stdint.h>

// out[b,p] = mean_d( probes[p,d] <= X[b,d] ? 1.0 : X[b,d] )
// B=2048, P=512, D=256, f32 in/out. VALU-bound (no fp32 MFMA on CDNA4).

#define BATCH  2048
#define NPROBE 512
#define DIM    256

#define BT 64          // batch tile per block
#define PT 64          // probe tile per block
#define DC 64          // d-chunk staged per buffer
#define NQ (DC / 4)    // 16B quads per row-chunk
#define NCHUNK (DIM / DC)

typedef float f4 __attribute__((ext_vector_type(4)));

static __device__ __forceinline__ void gl_lds16(const float* g, float* l) {
  // async global->LDS, 16B per lane; LDS dest is wave-uniform base + lane*16
  __builtin_amdgcn_global_load_lds(
      (const __attribute__((address_space(1))) void*)g,
      (__attribute__((address_space(3))) void*)l, 16, 0, 0);
}

__global__ __launch_bounds__(256)
void yoneda_kernel(const float* __restrict__ X, const float* __restrict__ Pr,
                   float* __restrict__ out) {
  // LDS layout: row-major [row][64 floats], linear (global_load_lds needs
  // linear dest). Bank-conflict fix: slot (r, q) holds global quad q^(r&7)
  // -- swizzle applied on the global SOURCE address at stage time and on
  // the READ index at compute time (both-sides pattern).
  __shared__ float Xs[2][BT * DC];   // 2 x 16 KB
  __shared__ float Ps[2][PT * DC];   // 2 x 16 KB   (total 64 KB)

  const int tid = threadIdx.x;
  const int tb  = tid >> 4;    // 0..15
  const int tp  = tid & 15;    // 0..15
  const int b0  = blockIdx.y * BT;
  const int p0  = blockIdx.x * PT;

  float acc[4][4];
  #pragma unroll
  for (int i = 0; i < 4; ++i)
    #pragma unroll
    for (int j = 0; j < 4; ++j) acc[i][j] = 0.0f;

  // per-thread rows: b = b0 + tb + 16*i, p = p0 + tp + 16*j
  // (tb+16i)&7 == tb&7 for all i -> one swizzle constant per side
  const int sxc = tb & 7;
  const int spc = tp & 7;

  int xbase[4], pbase[4];
  #pragma unroll
  for (int i = 0; i < 4; ++i) {
    xbase[i] = (tb + 16 * i) * DC;
    pbase[i] = (tp + 16 * i) * DC;
  }

  // ---- stage chunk 0 into buf 0 (4 passes x 256 threads x 16B per array)
  #pragma unroll
  for (int s = 0; s < 4; ++s) {
    int f16 = s * 256 + tid;        // 16B-chunk index in [0,1024)
    int r   = f16 >> 4;             // row 0..63
    int q   = f16 & 15;             // quad within row
    int qs  = q ^ (r & 7);          // inverse-swizzled global quad
    gl_lds16(X  + (size_t)(b0 + r) * DIM + 4 * qs, &Xs[0][f16 * 4]);
    gl_lds16(Pr + (size_t)(p0 + r) * DIM + 4 * qs, &Ps[0][f16 * 4]);
  }

  #pragma unroll 1
  for (int c = 0; c < NCHUNK; ++c) {
    const int buf = c & 1;
    // barrier drains vmcnt(0): chunk c's staging (issued last iter or
    // prologue) is complete; all waves done reading buf^1 from iter c-1.
    __syncthreads();

    if (c + 1 < NCHUNK) {
      const int dbase = (c + 1) * DC;
      #pragma unroll
      for (int s = 0; s < 4; ++s) {
        int f16 = s * 256 + tid;
        int r   = f16 >> 4;
        int q   = f16 & 15;
        int qs  = q ^ (r & 7);
        gl_lds16(X  + (size_t)(b0 + r) * DIM + dbase + 4 * qs,
                 &Xs[buf ^ 1][f16 * 4]);
        gl_lds16(Pr + (size_t)(p0 + r) * DIM + dbase + 4 * qs,
                 &Ps[buf ^ 1][f16 * 4]);
      }
    }

    const float* Xb = &Xs[buf][0];
    const float* Pb = &Ps[buf][0];

    #pragma unroll 4
    for (int Q = 0; Q < NQ; ++Q) {
      f4 xv[4], pv[4];
      #pragma unroll
      for (int i = 0; i < 4; ++i)
        xv[i] = *(const f4*)&Xb[xbase[i] + 4 * (Q ^ sxc)];
      #pragma unroll
      for (int j = 0; j < 4; ++j)
        pv[j] = *(const f4*)&Pb[pbase[j] + 4 * (Q ^ spc)];
      #pragma unroll
      for (int i = 0; i < 4; ++i)
        #pragma unroll
        for (int j = 0; j < 4; ++j)
          #pragma unroll
          for (int e = 0; e < 4; ++e) {
            float x = xv[i][e];
            float p = pv[j][e];
            acc[i][j] += (p <= x) ? 1.0f : x;   // cmp + cndmask + add
          }
    }
  }

  const float inv = 1.0f / (float)DIM;
  #pragma unroll
  for (int i = 0; i < 4; ++i) {
    size_t rowoff = (size_t)(b0 + tb + 16 * i) * NPROBE + p0 + tp;
    #pragma unroll
    for (int j = 0; j < 4; ++j)
      out[rowoff + 16 * j] = acc[i][j] * inv;   // lanes tp consecutive -> coalesced
  }
}

extern "C" void kernel_launch(void* const* d_in, const int* in_sizes, int n_in,
                              void* d_out, int out_size, void* d_ws, size_t ws_size,
                              hipStream_t stream) {
  const float* X  = (const float*)d_in[0];   // (2048, 256) f32
  const float* Pr = (const float*)d_in[1];   // (512, 256) f32
  float* out = (float*)d_out;                // (2048, 512) f32
  dim3 grid(NPROBE / PT, BATCH / BT);        // (8, 32) = 256 blocks
  yoneda_kernel<<<grid, 256, 0, stream>>>(X, Pr, out);
}

// Round 2
// 27.266 us; speedup vs baseline: 1.4846x; 1.4846x over previous
//
#include <hip/hip_runtime.h>
#include <stdint.h>

// out[b,p] = mean_d( probes[p,d] <= X[b,d] ? 1.0 : X[b,d] )
// B=2048, P=512, D=256, f32. VALU-bound: floor = 805M lane-ops / 78.6T = 10.2us.
// Structure: 256 blocks (1/CU) x 1024 threads (16 waves/CU = 4/SIMD).
// Block computes a 64x64 output tile; the 4 thread-groups of 256 split D
// 4-ways (64 d each); partials combined via LDS at the end (fixed order,
// deterministic). Full X/P tiles staged once into 128 KiB LDS via
// global_load_lds(16B), XOR-swizzled on the SOURCE address (linear dest),
// un-swizzled on the read side (both-sides rule).

#define BATCH  2048
#define NPROBE 512
#define DIM    256
#define BT 64
#define PT 64

typedef float f4 __attribute__((ext_vector_type(4)));

static __device__ __forceinline__ void gl_lds16(const float* g, float* l) {
  __builtin_amdgcn_global_load_lds(
      (const __attribute__((address_space(1))) void*)g,
      (__attribute__((address_space(3))) void*)l, 16, 0, 0);
}

__global__ __launch_bounds__(1024, 4)
void yoneda_kernel(const float* __restrict__ X, const float* __restrict__ Pr,
                   float* __restrict__ out) {
  // 128 KiB: Xs = lds[0 .. 16384) as [64 rows][64 quads], Ps = lds[16384 ..)
  __shared__ float lds[32768];
  float* Xs = lds;
  float* Ps = lds + 64 * 64 * 4;

  const int tid = threadIdx.x;
  const int b0  = blockIdx.y * BT;
  const int p0  = blockIdx.x * PT;

  // ---- stage full tiles: 4096 quads per array / 1024 threads = 4 each
  #pragma unroll
  for (int s = 0; s < 4; ++s) {
    int idx = s * 1024 + tid;          // quad index [0,4096)
    int r   = idx >> 6;                // row 0..63
    int q   = idx & 63;                // quad slot within row
    int qs  = q ^ (r & 7);             // inverse-swizzled global quad
    gl_lds16(X  + (size_t)(b0 + r) * DIM + 4 * qs, &Xs[idx * 4]);
    gl_lds16(Pr + (size_t)(p0 + r) * DIM + 4 * qs, &Ps[idx * 4]);
  }

  const int g    = tid >> 8;           // d-quarter 0..3 (64 d's = 16 quads)
  const int gtid = tid & 255;
  const int tb   = gtid >> 4;          // 0..15
  const int tp   = gtid & 15;          // 0..15
  const int sxc  = tb & 7;
  const int spc  = tp & 7;
  const int qoff = g * 16;             // this group's quad range

  float acc[4][4];
  #pragma unroll
  for (int i = 0; i < 4; ++i)
    #pragma unroll
    for (int j = 0; j < 4; ++j) acc[i][j] = 0.0f;

  int xrow[4], prow[4];
  #pragma unroll
  for (int i = 0; i < 4; ++i) {
    xrow[i] = (tb + 16 * i) * DIM;     // float offsets into Xs
    prow[i] = (tp + 16 * i) * DIM;
  }

  __syncthreads();                     // staging vmcnt drained exactly once

  #pragma unroll 4
  for (int Q = 0; Q < 16; ++Q) {
    f4 xv[4], pv[4];
    #pragma unroll
    for (int i = 0; i < 4; ++i)
      xv[i] = *(const f4*)&Xs[xrow[i] + 4 * (qoff + (Q ^ sxc))];
    #pragma unroll
    for (int j = 0; j < 4; ++j)
      pv[j] = *(const f4*)&Ps[prow[j] + 4 * (qoff + (Q ^ spc))];
    #pragma unroll
    for (int i = 0; i < 4; ++i)
      #pragma unroll
      for (int j = 0; j < 4; ++j)
        #pragma unroll
        for (int e = 0; e < 4; ++e) {
          float x = xv[i][e];
          float p = pv[j][e];
          acc[i][j] += (p <= x) ? 1.0f : x;   // cmp + cndmask + add
        }
  }

  // ---- combine the 4 d-partials (fixed order -> deterministic)
  __syncthreads();                     // everyone done reading Xs/Ps
  // cbuf[e][gq][gtid]: 16*3*256 floats = 48 KiB, overlaid on lds
  if (g > 0) {
    #pragma unroll
    for (int e = 0; e < 16; ++e)
      lds[(e * 3 + (g - 1)) * 256 + gtid] = acc[e >> 2][e & 3];
  }
  __syncthreads();
  if (g == 0) {
    const float inv = 1.0f / 256.0f;
    #pragma unroll
    for (int i = 0; i < 4; ++i) {
      size_t ro = (size_t)(b0 + tb + 16 * i) * NPROBE + p0 + tp;
      #pragma unroll
      for (int j = 0; j < 4; ++j) {
        const int e = i * 4 + j;
        float v = acc[i][j]
                + lds[(e * 3 + 0) * 256 + gtid]
                + lds[(e * 3 + 1) * 256 + gtid]
                + lds[(e * 3 + 2) * 256 + gtid];
        out[ro + 16 * j] = v * inv;    // lanes tp consecutive -> coalesced
      }
    }
  }
}

extern "C" void kernel_launch(void* const* d_in, const int* in_sizes, int n_in,
                              void* d_out, int out_size, void* d_ws, size_t ws_size,
                              hipStream_t stream) {
  const float* X  = (const float*)d_in[0];   // (2048, 256) f32
  const float* Pr = (const float*)d_in[1];   // (512, 256) f32
  float* out = (float*)d_out;                // (2048, 512) f32
  dim3 grid(NPROBE / PT, BATCH / BT);        // (8, 32) = 256 blocks
  yoneda_kernel<<<grid, 1024, 0, stream>>>(X, Pr, out);
}